// Round 9
// baseline (172.817 us; speedup 1.0000x reference)
//
#include <hip/hip_runtime.h>
#include <hip/hip_bf16.h>

#define NH 4
#define BT 4096      // B*S
#define DD 1024
#define CK 16        // codebook dim
#define CS 8192      // codebook size

typedef float vfloat4 __attribute__((ext_vector_type(4)));

// ws layout (float offsets)
#define WS_STATS 0                      // [BT][2]          = 8192
#define WS_PART  8192                   // [4][BT][64]      = 1048576
#define WS_PROJN 1056768                // [NH][BT][16]     = 262144
#define WS_CBN   1318912                // [NH][CS][16]     = 524288

// ---------------- K1: per-row LayerNorm stats (mean, rstd) ----------------
__global__ __launch_bounds__(256) void k_stats(const float* __restrict__ x,
                                               float* __restrict__ stats) {
  const int lane = threadIdx.x & 63;
  const int row  = blockIdx.x * 4 + (threadIdx.x >> 6);
  const float4* xr = reinterpret_cast<const float4*>(x + (size_t)row * DD);
  float4 v[4];
  float s = 0.f;
#pragma unroll
  for (int i = 0; i < 4; ++i) {
    v[i] = xr[lane + 64 * i];
    s += (v[i].x + v[i].y) + (v[i].z + v[i].w);
  }
#pragma unroll
  for (int m = 32; m >= 1; m >>= 1) s += __shfl_xor(s, m, 64);
  const float mean = s * (1.f / DD);
  float vs = 0.f;
#pragma unroll
  for (int i = 0; i < 4; ++i) {
    float a = v[i].x - mean, b = v[i].y - mean, c = v[i].z - mean, d = v[i].w - mean;
    vs += (a * a + b * b) + (c * c + d * d);
  }
#pragma unroll
  for (int m = 32; m >= 1; m >>= 1) vs += __shfl_xor(vs, m, 64);
  if (lane == 0) {
    stats[2 * row]     = mean;
    stats[2 * row + 1] = rsqrtf(vs * (1.f / DD) + 1e-5f);
  }
}

// ------------- K2: LN + projection, register-tiled, d-split x4 -------------
__global__ __launch_bounds__(256) void k_proj(const float* __restrict__ x,
                                              const float* __restrict__ stats,
                                              const float* __restrict__ P,
                                              float* __restrict__ part) {
  __shared__ float xa[32][68];   // [d][row]
  __shared__ float pa[32][68];   // [d][o=h*16+k]
  const int tile = blockIdx.x & 63;
  const int ds   = blockIdx.x >> 6;
  const int tid  = threadIdx.x;
  const int tx = tid & 15, ty = tid >> 4;
  const int r0 = ty * 4, o0 = tx * 4;
  float acc[4][4] = {};

  for (int dc = 0; dc < 256; dc += 32) {
    const int d0 = ds * 256 + dc;
    {
      const int row  = tid >> 2;
      const int rowg = tile * 64 + row;
      const float mean = stats[2 * rowg];
      const float rstd = stats[2 * rowg + 1];
      const float* xp = x + (size_t)rowg * DD + d0 + (tid & 3) * 8;
      float4 a = reinterpret_cast<const float4*>(xp)[0];
      float4 b = reinterpret_cast<const float4*>(xp)[1];
      const int dd = (tid & 3) * 8;
      xa[dd + 0][row] = (a.x - mean) * rstd;
      xa[dd + 1][row] = (a.y - mean) * rstd;
      xa[dd + 2][row] = (a.z - mean) * rstd;
      xa[dd + 3][row] = (a.w - mean) * rstd;
      xa[dd + 4][row] = (b.x - mean) * rstd;
      xa[dd + 5][row] = (b.y - mean) * rstd;
      xa[dd + 6][row] = (b.z - mean) * rstd;
      xa[dd + 7][row] = (b.w - mean) * rstd;
    }
    {
      const int h  = tid >> 6;
      const int f0 = (tid & 63) * 8;
      const float* pp = P + (size_t)h * DD * CK + (size_t)d0 * CK + f0;
      float4 a = reinterpret_cast<const float4*>(pp)[0];
      float4 b = reinterpret_cast<const float4*>(pp)[1];
      float vv[8] = {a.x, a.y, a.z, a.w, b.x, b.y, b.z, b.w};
#pragma unroll
      for (int j = 0; j < 8; ++j) {
        int f = f0 + j;
        pa[f >> 4][(h << 4) | (f & 15)] = vv[j];
      }
    }
    __syncthreads();
#pragma unroll
    for (int d = 0; d < 32; ++d) {
      float4 xv = *reinterpret_cast<const float4*>(&xa[d][r0]);
      float4 pv = *reinterpret_cast<const float4*>(&pa[d][o0]);
      float xr[4] = {xv.x, xv.y, xv.z, xv.w};
      float pr[4] = {pv.x, pv.y, pv.z, pv.w};
#pragma unroll
      for (int i = 0; i < 4; ++i)
#pragma unroll
        for (int j = 0; j < 4; ++j) acc[i][j] = fmaf(xr[i], pr[j], acc[i][j]);
    }
    __syncthreads();
  }
  float* pb = part + ((size_t)ds * BT + tile * 64) * 64;
#pragma unroll
  for (int i = 0; i < 4; ++i) {
    float4 o = {acc[i][0], acc[i][1], acc[i][2], acc[i][3]};
    *reinterpret_cast<float4*>(pb + (size_t)(r0 + i) * 64 + o0) = o;
  }
}

// ---------- K3: sum d-split partials, cosine-normalize projections ----------
__global__ __launch_bounds__(256) void k_norm(const float* __restrict__ part,
                                              float* __restrict__ proj_n) {
  const int t   = blockIdx.x * 256 + threadIdx.x;
  const int row = t >> 2, h = t & 3;
  float s[16];
#pragma unroll
  for (int k = 0; k < 16; ++k) s[k] = 0.f;
#pragma unroll
  for (int ds = 0; ds < 4; ++ds) {
    const float* pb = part + (size_t)ds * BT * 64 + (size_t)row * 64 + h * 16;
#pragma unroll
    for (int w = 0; w < 4; ++w) {
      float4 v = reinterpret_cast<const float4*>(pb)[w];
      s[w * 4 + 0] += v.x; s[w * 4 + 1] += v.y; s[w * 4 + 2] += v.z; s[w * 4 + 3] += v.w;
    }
  }
  float nsq = 0.f;
#pragma unroll
  for (int k = 0; k < 16; ++k) nsq = fmaf(s[k], s[k], nsq);
  const float inv = 1.f / fmaxf(sqrtf(nsq), 1e-8f);
  float* op = proj_n + ((size_t)h * BT + row) * 16;
#pragma unroll
  for (int w = 0; w < 4; ++w) {
    float4 v = {s[w*4+0] * inv, s[w*4+1] * inv, s[w*4+2] * inv, s[w*4+3] * inv};
    reinterpret_cast<float4*>(op)[w] = v;
  }
}

// ---------------- K4: normalize codebook rows ----------------
__global__ __launch_bounds__(256) void k_cbn(const float* __restrict__ CB,
                                             float* __restrict__ cb_n) {
  const int t = blockIdx.x * 256 + threadIdx.x;
  const float4* src = reinterpret_cast<const float4*>(CB + (size_t)t * 16);
  float4 v[4];
  float nsq = 0.f;
#pragma unroll
  for (int w = 0; w < 4; ++w) {
    v[w] = src[w];
    nsq = fmaf(v[w].x, v[w].x, nsq); nsq = fmaf(v[w].y, v[w].y, nsq);
    nsq = fmaf(v[w].z, v[w].z, nsq); nsq = fmaf(v[w].w, v[w].w, nsq);
  }
  const float inv = 1.f / fmaxf(sqrtf(nsq), 1e-8f);
  float4* dst = reinterpret_cast<float4*>(cb_n + (size_t)t * 16);
#pragma unroll
  for (int w = 0; w < 4; ++w) {
    float4 o = {v[w].x * inv, v[w].y * inv, v[w].z * inv, v[w].w * inv};
    dst[w] = o;
  }
}

// -------- K5: distances + argmax.  grid = h(4) x tile(512 of 8 rows) --------
// 4 codes/thread/chunk, 8 chunks. Software-pipelined q: row r's fenced region
// issues ds_reads for row r+1 BEFORE row r's FMAs (qa/qb double buffer,
// static names) -> counted lgkmcnt, no per-row LDS stall. NT dwordx4 stores.
// sched_barrier(0) per row bounds live ranges (round-4: no fence => spill).
#define QLOAD(Q0, Q1, Q2, Q3, r)                              \
  Q0 = *reinterpret_cast<const float4*>(&q[(r)][0]);          \
  Q1 = *reinterpret_cast<const float4*>(&q[(r)][4]);          \
  Q2 = *reinterpret_cast<const float4*>(&q[(r)][8]);          \
  Q3 = *reinterpret_cast<const float4*>(&q[(r)][12]);

#define ROWBODY(r, Q0, Q1, Q2, Q3)                                         \
  {                                                                        \
    float dj[4];                                                           \
    _Pragma("unroll")                                                      \
    for (int j = 0; j < 4; ++j) {                                          \
      float s =        cb[j][0].x * Q0.x;                                  \
      s = fmaf(cb[j][0].y, Q0.y, s);                                       \
      s = fmaf(cb[j][0].z, Q0.z, s);                                       \
      s = fmaf(cb[j][0].w, Q0.w, s);                                       \
      s = fmaf(cb[j][1].x, Q1.x, s);                                       \
      s = fmaf(cb[j][1].y, Q1.y, s);                                       \
      s = fmaf(cb[j][1].z, Q1.z, s);                                       \
      s = fmaf(cb[j][1].w, Q1.w, s);                                       \
      s = fmaf(cb[j][2].x, Q2.x, s);                                       \
      s = fmaf(cb[j][2].y, Q2.y, s);                                       \
      s = fmaf(cb[j][2].z, Q2.z, s);                                       \
      s = fmaf(cb[j][2].w, Q2.w, s);                                       \
      s = fmaf(cb[j][3].x, Q3.x, s);                                       \
      s = fmaf(cb[j][3].y, Q3.y, s);                                       \
      s = fmaf(cb[j][3].z, Q3.z, s);                                       \
      s = fmaf(cb[j][3].w, Q3.w, s);                                       \
      dj[j] = s;                                                           \
    }                                                                      \
    vfloat4 dots = {dj[0], dj[1], dj[2], dj[3]};                           \
    __builtin_nontemporal_store(dots,                                      \
        reinterpret_cast<vfloat4*>(db + (size_t)(r) * CS + c));            \
    _Pragma("unroll")                                                      \
    for (int j = 0; j < 4; ++j) {                                          \
      if (dj[j] > best[(r)]) { best[(r)] = dj[j]; bidx[(r)] = c + j; }     \
    }                                                                      \
  }                                                                        \
  __builtin_amdgcn_sched_barrier(0);

__global__ __launch_bounds__(256, 3) void k_dist(const float* __restrict__ proj_n,
                                                 const float* __restrict__ cb_n,
                                                 float* __restrict__ dist,
                                                 float* __restrict__ idx_out) {
  __shared__ float q[8][16];
  __shared__ float redv[8][4];
  __shared__ int   redi[8][4];
  const int h    = blockIdx.x >> 9;
  const int tile = blockIdx.x & 511;
  const int tid  = threadIdx.x;

  if (tid < 32) {
    const int r = tid >> 2, k4 = tid & 3;
    float4 v = *reinterpret_cast<const float4*>(
        proj_n + ((size_t)h * BT + tile * 8 + r) * 16 + k4 * 4);
    *reinterpret_cast<float4*>(&q[r][k4 * 4]) = v;
  }
  __syncthreads();

  float best[8];
  int   bidx[8];
#pragma unroll
  for (int r = 0; r < 8; ++r) { best[r] = -2e30f; bidx[r] = 0; }

  const float* cbh = cb_n + (size_t)h * CS * CK;
  float* db = dist + ((size_t)h * BT + tile * 8) * CS;

  for (int cc = 0; cc < 8; ++cc) {
    const int c = cc * 1024 + tid * 4;
    float4 cb[4][4];
    const float4* cs = reinterpret_cast<const float4*>(cbh + (size_t)c * CK);
#pragma unroll
    for (int j = 0; j < 4; ++j)
#pragma unroll
      for (int w = 0; w < 4; ++w) cb[j][w] = cs[j * 4 + w];

    float4 qa0, qa1, qa2, qa3, qb0, qb1, qb2, qb3;
    QLOAD(qa0, qa1, qa2, qa3, 0)
    QLOAD(qb0, qb1, qb2, qb3, 1) ROWBODY(0, qa0, qa1, qa2, qa3)
    QLOAD(qa0, qa1, qa2, qa3, 2) ROWBODY(1, qb0, qb1, qb2, qb3)
    QLOAD(qb0, qb1, qb2, qb3, 3) ROWBODY(2, qa0, qa1, qa2, qa3)
    QLOAD(qa0, qa1, qa2, qa3, 4) ROWBODY(3, qb0, qb1, qb2, qb3)
    QLOAD(qb0, qb1, qb2, qb3, 5) ROWBODY(4, qa0, qa1, qa2, qa3)
    QLOAD(qa0, qa1, qa2, qa3, 6) ROWBODY(5, qb0, qb1, qb2, qb3)
    QLOAD(qb0, qb1, qb2, qb3, 7) ROWBODY(6, qa0, qa1, qa2, qa3)
    ROWBODY(7, qb0, qb1, qb2, qb3)
  }

  // reduction: wave shuffle then LDS across the 4 waves
  const int lane = tid & 63, wv = tid >> 6;
#pragma unroll
  for (int r = 0; r < 8; ++r) {
    float v = best[r];
    int   ii = bidx[r];
#pragma unroll
    for (int m = 32; m >= 1; m >>= 1) {
      float ov = __shfl_xor(v, m, 64);
      int   oi = __shfl_xor(ii, m, 64);
      if (ov > v || (ov == v && oi < ii)) { v = ov; ii = oi; }
    }
    if (lane == 0) { redv[r][wv] = v; redi[r][wv] = ii; }
  }
  __syncthreads();
  if (tid < 8) {
    const int r = tid;
    float v = redv[r][0];
    int   ii = redi[r][0];
#pragma unroll
    for (int w = 1; w < 4; ++w) {
      float ov = redv[r][w];
      int   oi = redi[r][w];
      if (ov > v || (ov == v && oi < ii)) { v = ov; ii = oi; }
    }
    const int rowg = tile * 8 + r;
    idx_out[(size_t)rowg * 4 + h] = (float)ii;
  }
}

extern "C" void kernel_launch(void* const* d_in, const int* in_sizes, int n_in,
                              void* d_out, int out_size, void* d_ws, size_t ws_size,
                              hipStream_t stream) {
  (void)in_sizes; (void)n_in; (void)out_size; (void)ws_size;
  const float* x  = (const float*)d_in[0];
  const float* P  = (const float*)d_in[1];
  const float* CB = (const float*)d_in[2];
  float* ws  = (float*)d_ws;
  float* out = (float*)d_out;
  float* idx_out = out;             // (b,t,h) as float: 16384
  float* dist    = out + BT * NH;   // (h,b,t,c): 134217728

  k_stats<<<1024, 256, 0, stream>>>(x, ws + WS_STATS);
  k_proj <<<256,  256, 0, stream>>>(x, ws + WS_STATS, P, ws + WS_PART);
  k_norm <<<64,   256, 0, stream>>>(ws + WS_PART, ws + WS_PROJN);
  k_cbn  <<<128,  256, 0, stream>>>(CB, ws + WS_CBN);
  k_dist <<<2048, 256, 0, stream>>>(ws + WS_PROJN, ws + WS_CBN, dist, idx_out);
}

// Round 10
// 144.821 us; speedup vs baseline: 1.1933x; 1.1933x over previous
//
#include <hip/hip_runtime.h>
#include <hip/hip_bf16.h>

#define NH 4
#define BT 4096      // B*S
#define DD 1024
#define CK 16        // codebook dim
#define CS 8192      // codebook size

typedef float vfloat4 __attribute__((ext_vector_type(4)));

// ws layout (float offsets)
#define WS_STATS 0                      // [BT][2]          = 8192
#define WS_PART  8192                   // [4][BT][64]      = 1048576
#define WS_PROJN 1056768                // [NH][BT][16]     = 262144
#define WS_CBN   1318912                // [NH][CS][16]     = 524288

// ---------------- K1: per-row LayerNorm stats (mean, rstd) ----------------
__global__ __launch_bounds__(256) void k_stats(const float* __restrict__ x,
                                               float* __restrict__ stats) {
  const int lane = threadIdx.x & 63;
  const int row  = blockIdx.x * 4 + (threadIdx.x >> 6);
  const float4* xr = reinterpret_cast<const float4*>(x + (size_t)row * DD);
  float4 v[4];
  float s = 0.f;
#pragma unroll
  for (int i = 0; i < 4; ++i) {
    v[i] = xr[lane + 64 * i];
    s += (v[i].x + v[i].y) + (v[i].z + v[i].w);
  }
#pragma unroll
  for (int m = 32; m >= 1; m >>= 1) s += __shfl_xor(s, m, 64);
  const float mean = s * (1.f / DD);
  float vs = 0.f;
#pragma unroll
  for (int i = 0; i < 4; ++i) {
    float a = v[i].x - mean, b = v[i].y - mean, c = v[i].z - mean, d = v[i].w - mean;
    vs += (a * a + b * b) + (c * c + d * d);
  }
#pragma unroll
  for (int m = 32; m >= 1; m >>= 1) vs += __shfl_xor(vs, m, 64);
  if (lane == 0) {
    stats[2 * row]     = mean;
    stats[2 * row + 1] = rsqrtf(vs * (1.f / DD) + 1e-5f);
  }
}

// ------------- K2: LN + projection, register-tiled, d-split x4 -------------
__global__ __launch_bounds__(256) void k_proj(const float* __restrict__ x,
                                              const float* __restrict__ stats,
                                              const float* __restrict__ P,
                                              float* __restrict__ part) {
  __shared__ float xa[32][68];   // [d][row]
  __shared__ float pa[32][68];   // [d][o=h*16+k]
  const int tile = blockIdx.x & 63;
  const int ds   = blockIdx.x >> 6;
  const int tid  = threadIdx.x;
  const int tx = tid & 15, ty = tid >> 4;
  const int r0 = ty * 4, o0 = tx * 4;
  float acc[4][4] = {};

  for (int dc = 0; dc < 256; dc += 32) {
    const int d0 = ds * 256 + dc;
    {
      const int row  = tid >> 2;
      const int rowg = tile * 64 + row;
      const float mean = stats[2 * rowg];
      const float rstd = stats[2 * rowg + 1];
      const float* xp = x + (size_t)rowg * DD + d0 + (tid & 3) * 8;
      float4 a = reinterpret_cast<const float4*>(xp)[0];
      float4 b = reinterpret_cast<const float4*>(xp)[1];
      const int dd = (tid & 3) * 8;
      xa[dd + 0][row] = (a.x - mean) * rstd;
      xa[dd + 1][row] = (a.y - mean) * rstd;
      xa[dd + 2][row] = (a.z - mean) * rstd;
      xa[dd + 3][row] = (a.w - mean) * rstd;
      xa[dd + 4][row] = (b.x - mean) * rstd;
      xa[dd + 5][row] = (b.y - mean) * rstd;
      xa[dd + 6][row] = (b.z - mean) * rstd;
      xa[dd + 7][row] = (b.w - mean) * rstd;
    }
    {
      const int h  = tid >> 6;
      const int f0 = (tid & 63) * 8;
      const float* pp = P + (size_t)h * DD * CK + (size_t)d0 * CK + f0;
      float4 a = reinterpret_cast<const float4*>(pp)[0];
      float4 b = reinterpret_cast<const float4*>(pp)[1];
      float vv[8] = {a.x, a.y, a.z, a.w, b.x, b.y, b.z, b.w};
#pragma unroll
      for (int j = 0; j < 8; ++j) {
        int f = f0 + j;
        pa[f >> 4][(h << 4) | (f & 15)] = vv[j];
      }
    }
    __syncthreads();
#pragma unroll
    for (int d = 0; d < 32; ++d) {
      float4 xv = *reinterpret_cast<const float4*>(&xa[d][r0]);
      float4 pv = *reinterpret_cast<const float4*>(&pa[d][o0]);
      float xr[4] = {xv.x, xv.y, xv.z, xv.w};
      float pr[4] = {pv.x, pv.y, pv.z, pv.w};
#pragma unroll
      for (int i = 0; i < 4; ++i)
#pragma unroll
        for (int j = 0; j < 4; ++j) acc[i][j] = fmaf(xr[i], pr[j], acc[i][j]);
    }
    __syncthreads();
  }
  float* pb = part + ((size_t)ds * BT + tile * 64) * 64;
#pragma unroll
  for (int i = 0; i < 4; ++i) {
    float4 o = {acc[i][0], acc[i][1], acc[i][2], acc[i][3]};
    *reinterpret_cast<float4*>(pb + (size_t)(r0 + i) * 64 + o0) = o;
  }
}

// ---------- K3: sum d-split partials, cosine-normalize projections ----------
__global__ __launch_bounds__(256) void k_norm(const float* __restrict__ part,
                                              float* __restrict__ proj_n) {
  const int t   = blockIdx.x * 256 + threadIdx.x;
  const int row = t >> 2, h = t & 3;
  float s[16];
#pragma unroll
  for (int k = 0; k < 16; ++k) s[k] = 0.f;
#pragma unroll
  for (int ds = 0; ds < 4; ++ds) {
    const float* pb = part + (size_t)ds * BT * 64 + (size_t)row * 64 + h * 16;
#pragma unroll
    for (int w = 0; w < 4; ++w) {
      float4 v = reinterpret_cast<const float4*>(pb)[w];
      s[w * 4 + 0] += v.x; s[w * 4 + 1] += v.y; s[w * 4 + 2] += v.z; s[w * 4 + 3] += v.w;
    }
  }
  float nsq = 0.f;
#pragma unroll
  for (int k = 0; k < 16; ++k) nsq = fmaf(s[k], s[k], nsq);
  const float inv = 1.f / fmaxf(sqrtf(nsq), 1e-8f);
  float* op = proj_n + ((size_t)h * BT + row) * 16;
#pragma unroll
  for (int w = 0; w < 4; ++w) {
    float4 v = {s[w*4+0] * inv, s[w*4+1] * inv, s[w*4+2] * inv, s[w*4+3] * inv};
    reinterpret_cast<float4*>(op)[w] = v;
  }
}

// ---------------- K4: normalize codebook rows ----------------
__global__ __launch_bounds__(256) void k_cbn(const float* __restrict__ CB,
                                             float* __restrict__ cb_n) {
  const int t = blockIdx.x * 256 + threadIdx.x;
  const float4* src = reinterpret_cast<const float4*>(CB + (size_t)t * 16);
  float4 v[4];
  float nsq = 0.f;
#pragma unroll
  for (int w = 0; w < 4; ++w) {
    v[w] = src[w];
    nsq = fmaf(v[w].x, v[w].x, nsq); nsq = fmaf(v[w].y, v[w].y, nsq);
    nsq = fmaf(v[w].z, v[w].z, nsq); nsq = fmaf(v[w].w, v[w].w, nsq);
  }
  const float inv = 1.f / fmaxf(sqrtf(nsq), 1e-8f);
  float4* dst = reinterpret_cast<float4*>(cb_n + (size_t)t * 16);
#pragma unroll
  for (int w = 0; w < 4; ++w) {
    float4 o = {v[w].x * inv, v[w].y * inv, v[w].z * inv, v[w].w * inv};
    dst[w] = o;
  }
}

// -------- K5: distances + argmax.  grid = h(4) x tile(256 of 16 rows) --------
// q rows are block-uniform: read them from GLOBAL (L1 broadcast), not LDS --
// zero LDS pipe traffic in the hot loop. Software-pipelined 1 row ahead with
// named A/B float4 sets. NT dwordx4 stores. sched_barrier(0) per row bounds
// live ranges (round-4 lesson: no fence => 256 VGPR + scratch spill).
#define QLOADG(Q0, Q1, Q2, Q3, r)  \
  Q0 = qg[4 * (r) + 0];            \
  Q1 = qg[4 * (r) + 1];            \
  Q2 = qg[4 * (r) + 2];            \
  Q3 = qg[4 * (r) + 3];

#define ROWBODY(r, Q0, Q1, Q2, Q3)                                         \
  {                                                                        \
    float dj[4];                                                           \
    _Pragma("unroll")                                                      \
    for (int j = 0; j < 4; ++j) {                                          \
      float s =        cb[j][0].x * Q0.x;                                  \
      s = fmaf(cb[j][0].y, Q0.y, s);                                       \
      s = fmaf(cb[j][0].z, Q0.z, s);                                       \
      s = fmaf(cb[j][0].w, Q0.w, s);                                       \
      s = fmaf(cb[j][1].x, Q1.x, s);                                       \
      s = fmaf(cb[j][1].y, Q1.y, s);                                       \
      s = fmaf(cb[j][1].z, Q1.z, s);                                       \
      s = fmaf(cb[j][1].w, Q1.w, s);                                       \
      s = fmaf(cb[j][2].x, Q2.x, s);                                       \
      s = fmaf(cb[j][2].y, Q2.y, s);                                       \
      s = fmaf(cb[j][2].z, Q2.z, s);                                       \
      s = fmaf(cb[j][2].w, Q2.w, s);                                       \
      s = fmaf(cb[j][3].x, Q3.x, s);                                       \
      s = fmaf(cb[j][3].y, Q3.y, s);                                       \
      s = fmaf(cb[j][3].z, Q3.z, s);                                       \
      s = fmaf(cb[j][3].w, Q3.w, s);                                       \
      dj[j] = s;                                                           \
    }                                                                      \
    vfloat4 dots = {dj[0], dj[1], dj[2], dj[3]};                           \
    __builtin_nontemporal_store(dots,                                      \
        reinterpret_cast<vfloat4*>(db + (size_t)(r) * CS + c));            \
    _Pragma("unroll")                                                      \
    for (int j = 0; j < 4; ++j) {                                          \
      if (dj[j] > best[(r)]) { best[(r)] = dj[j]; bidx[(r)] = c + j; }     \
    }                                                                      \
  }                                                                        \
  __builtin_amdgcn_sched_barrier(0);

__global__ __launch_bounds__(256, 3) void k_dist(const float* __restrict__ proj_n,
                                                 const float* __restrict__ cb_n,
                                                 float* __restrict__ dist,
                                                 float* __restrict__ idx_out) {
  __shared__ float redv[16][4];
  __shared__ int   redi[16][4];
  const int h    = blockIdx.x >> 8;
  const int tile = blockIdx.x & 255;
  const int tid  = threadIdx.x;

  float best[16];
  int   bidx[16];
#pragma unroll
  for (int r = 0; r < 16; ++r) { best[r] = -2e30f; bidx[r] = 0; }

  const float* cbh = cb_n + (size_t)h * CS * CK;
  const float4* qg = reinterpret_cast<const float4*>(
      proj_n + ((size_t)h * BT + tile * 16) * 16);
  float* db = dist + ((size_t)h * BT + tile * 16) * CS;

  for (int cc = 0; cc < 8; ++cc) {
    const int c = cc * 1024 + tid * 4;
    float4 cb[4][4];
    const float4* cs = reinterpret_cast<const float4*>(cbh + (size_t)c * CK);
#pragma unroll
    for (int j = 0; j < 4; ++j)
#pragma unroll
      for (int w = 0; w < 4; ++w) cb[j][w] = cs[j * 4 + w];

    float4 qa0, qa1, qa2, qa3, qb0, qb1, qb2, qb3;
    QLOADG(qa0, qa1, qa2, qa3, 0)
    QLOADG(qb0, qb1, qb2, qb3, 1)  ROWBODY(0,  qa0, qa1, qa2, qa3)
    QLOADG(qa0, qa1, qa2, qa3, 2)  ROWBODY(1,  qb0, qb1, qb2, qb3)
    QLOADG(qb0, qb1, qb2, qb3, 3)  ROWBODY(2,  qa0, qa1, qa2, qa3)
    QLOADG(qa0, qa1, qa2, qa3, 4)  ROWBODY(3,  qb0, qb1, qb2, qb3)
    QLOADG(qb0, qb1, qb2, qb3, 5)  ROWBODY(4,  qa0, qa1, qa2, qa3)
    QLOADG(qa0, qa1, qa2, qa3, 6)  ROWBODY(5,  qb0, qb1, qb2, qb3)
    QLOADG(qb0, qb1, qb2, qb3, 7)  ROWBODY(6,  qa0, qa1, qa2, qa3)
    QLOADG(qa0, qa1, qa2, qa3, 8)  ROWBODY(7,  qb0, qb1, qb2, qb3)
    QLOADG(qb0, qb1, qb2, qb3, 9)  ROWBODY(8,  qa0, qa1, qa2, qa3)
    QLOADG(qa0, qa1, qa2, qa3, 10) ROWBODY(9,  qb0, qb1, qb2, qb3)
    QLOADG(qb0, qb1, qb2, qb3, 11) ROWBODY(10, qa0, qa1, qa2, qa3)
    QLOADG(qa0, qa1, qa2, qa3, 12) ROWBODY(11, qb0, qb1, qb2, qb3)
    QLOADG(qb0, qb1, qb2, qb3, 13) ROWBODY(12, qa0, qa1, qa2, qa3)
    QLOADG(qa0, qa1, qa2, qa3, 14) ROWBODY(13, qb0, qb1, qb2, qb3)
    QLOADG(qb0, qb1, qb2, qb3, 15) ROWBODY(14, qa0, qa1, qa2, qa3)
    ROWBODY(15, qb0, qb1, qb2, qb3)
  }

  // reduction: wave shuffle then LDS across the 4 waves
  const int lane = tid & 63, wv = tid >> 6;
#pragma unroll
  for (int r = 0; r < 16; ++r) {
    float v = best[r];
    int   ii = bidx[r];
#pragma unroll
    for (int m = 32; m >= 1; m >>= 1) {
      float ov = __shfl_xor(v, m, 64);
      int   oi = __shfl_xor(ii, m, 64);
      if (ov > v || (ov == v && oi < ii)) { v = ov; ii = oi; }
    }
    if (lane == 0) { redv[r][wv] = v; redi[r][wv] = ii; }
  }
  __syncthreads();
  if (tid < 16) {
    const int r = tid;
    float v = redv[r][0];
    int   ii = redi[r][0];
#pragma unroll
    for (int w = 1; w < 4; ++w) {
      float ov = redv[r][w];
      int   oi = redi[r][w];
      if (ov > v || (ov == v && oi < ii)) { v = ov; ii = oi; }
    }
    const int rowg = tile * 16 + r;
    idx_out[(size_t)rowg * 4 + h] = (float)ii;
  }
}

extern "C" void kernel_launch(void* const* d_in, const int* in_sizes, int n_in,
                              void* d_out, int out_size, void* d_ws, size_t ws_size,
                              hipStream_t stream) {
  (void)in_sizes; (void)n_in; (void)out_size; (void)ws_size;
  const float* x  = (const float*)d_in[0];
  const float* P  = (const float*)d_in[1];
  const float* CB = (const float*)d_in[2];
  float* ws  = (float*)d_ws;
  float* out = (float*)d_out;
  float* idx_out = out;             // (b,t,h) as float: 16384
  float* dist    = out + BT * NH;   // (h,b,t,c): 134217728

  k_stats<<<1024, 256, 0, stream>>>(x, ws + WS_STATS);
  k_proj <<<256,  256, 0, stream>>>(x, ws + WS_STATS, P, ws + WS_PART);
  k_norm <<<64,   256, 0, stream>>>(ws + WS_PART, ws + WS_PROJN);
  k_cbn  <<<128,  256, 0, stream>>>(CB, ws + WS_CBN);
  k_dist <<<1024, 256, 0, stream>>>(ws + WS_PROJN, ws + WS_CBN, dist, idx_out);
}